// Round 4
// baseline (291.585 us; speedup 1.0000x reference)
//
#include <hip/hip_runtime.h>

// GraphConvolution: out = input @ W_self + (adj @ input) @ W_agg
//                       = adj @ (input @ W_agg) + input @ W_self   [associativity]
// Heavy op: adj(16384x16384 fp32, 1.07GB) @ Y(16384x128 bf16) -> memory-bound,
// floor ~168us @6.4TB/s.
//
// r4: BM=64 BK=256 (1KB/row/tile DRAM chunks), 256 blocks x 512 thr, 1 blk/CU.
//  - A: global_load_lds double-buffer 2x64KB, rule-21 XOR swizzle (chunk ^= row&7), NT policy
//  - B: NO LDS - asm global_load_dwordx4 from L2 into two 64-VGPR banks,
//    half-tile pipelined (load bank h+1 while computing bank h)
//  - counted vmcnt schedule (24/16), one s_barrier per BK=256 iter, 64 iters
//
// ws: [0,4MB) Yt bf16 pre-tiled in 128-row tiles: elem = H*16384 + (ch*128+n)*8 + kin,
//     H=m>>7, ch=(m>>3)&15, kin=m&7.   [4MB,12MB) Z fp32 row-major.

#define NROWS 16384
#define FDIM  128
#define NTI   64           // K iterations of BK=256 (two 128-row Yt half-tiles each)

typedef __attribute__((ext_vector_type(4))) float f32x4;
typedef __attribute__((ext_vector_type(8))) short short8;
typedef __attribute__((ext_vector_type(8))) __bf16 bf16x8;
typedef __attribute__((ext_vector_type(8))) unsigned short ushort8;

static __device__ __forceinline__ unsigned short f2bf(float f) {
  union { __bf16 b; unsigned short u; } cvt;
  cvt.b = (__bf16)f;   // RNE fptrunc
  return cvt.u;
}

// ---------------------------------------------------------------------------
// Kernel 1: Y = input @ W_agg (bf16, pre-tiled), Z = input @ W_self (fp32)
// ---------------------------------------------------------------------------
__global__ __launch_bounds__(256, 2)
void gcn_prep(const float* __restrict__ input, const float* __restrict__ weight,
              unsigned short* __restrict__ Yt, float* __restrict__ Z)
{
  __shared__ __align__(16) float in_lds[32 * FDIM];
  const int tid = threadIdx.x;
  const int m0  = blockIdx.x * 32;

  const f32x4* src = (const f32x4*)(input + (size_t)m0 * FDIM);
  f32x4* dst = (f32x4*)in_lds;
#pragma unroll
  for (int i = 0; i < 4; ++i) dst[i * 256 + tid] = src[i * 256 + tid];
  __syncthreads();

  const int c  = tid & 127;
  const int rg = tid >> 7;

  float accz[16], accy[16];
#pragma unroll
  for (int r = 0; r < 16; ++r) { accz[r] = 0.f; accy[r] = 0.f; }

  for (int k4 = 0; k4 < 32; ++k4) {
    float wsv[4], wav[4];
#pragma unroll
    for (int j = 0; j < 4; ++j) {
      wsv[j] = weight[(size_t)(k4 * 4 + j) * FDIM + c];
      wav[j] = weight[(size_t)(k4 * 4 + j + FDIM) * FDIM + c];
    }
#pragma unroll
    for (int r = 0; r < 16; ++r) {
      const f32x4 vin = *(const f32x4*)&in_lds[(rg * 16 + r) * FDIM + k4 * 4];
#pragma unroll
      for (int j = 0; j < 4; ++j) {
        accz[r] += vin[j] * wsv[j];
        accy[r] += vin[j] * wav[j];
      }
    }
  }

#pragma unroll
  for (int r = 0; r < 16; ++r)
    Z[(size_t)(m0 + rg * 16 + r) * FDIM + c] = accz[r];

  const int kt = m0 >> 7;   // 32-row block never straddles a 128-row tile
#pragma unroll
  for (int g = 0; g < 2; ++g) {
    const int mbase = m0 + rg * 16 + g * 8;
    const int ch = (mbase >> 3) & 15;
    ushort8 v;
#pragma unroll
    for (int j = 0; j < 8; ++j) v[j] = f2bf(accy[g * 8 + j]);
    *(ushort8*)&Yt[(size_t)kt * 16384 + (size_t)(ch * 128 + c) * 8] = v;
  }
}

// ---------------------------------------------------------------------------
// Kernel 2: out = adj @ Y + Z.  BM=64 BN=128 BK=256. 256 blocks x 512 thr.
// ---------------------------------------------------------------------------

// 16 B-frag loads (one 128-row half-tile) into a register bank, via L2.
#define BLOAD(BK_, H_)                                                                        \
  { const char* _bb = (const char*)Yt + (size_t)(H_) * 32768 + boff;                          \
    const char* _b0 = _bb;                                                                    \
    const char* _b1 = _bb + 8192;                                                             \
    const char* _b2 = _bb + 16384;                                                            \
    const char* _b3 = _bb + 24576;                                                            \
    asm volatile("global_load_dwordx4 %0, %1, off"            : "=v"(BK_[ 0]) : "v"(_b0));    \
    asm volatile("global_load_dwordx4 %0, %1, off offset:256" : "=v"(BK_[ 1]) : "v"(_b0));    \
    asm volatile("global_load_dwordx4 %0, %1, off offset:512" : "=v"(BK_[ 2]) : "v"(_b0));    \
    asm volatile("global_load_dwordx4 %0, %1, off offset:768" : "=v"(BK_[ 3]) : "v"(_b0));    \
    asm volatile("global_load_dwordx4 %0, %1, off"            : "=v"(BK_[ 4]) : "v"(_b1));    \
    asm volatile("global_load_dwordx4 %0, %1, off offset:256" : "=v"(BK_[ 5]) : "v"(_b1));    \
    asm volatile("global_load_dwordx4 %0, %1, off offset:512" : "=v"(BK_[ 6]) : "v"(_b1));    \
    asm volatile("global_load_dwordx4 %0, %1, off offset:768" : "=v"(BK_[ 7]) : "v"(_b1));    \
    asm volatile("global_load_dwordx4 %0, %1, off"            : "=v"(BK_[ 8]) : "v"(_b2));    \
    asm volatile("global_load_dwordx4 %0, %1, off offset:256" : "=v"(BK_[ 9]) : "v"(_b2));    \
    asm volatile("global_load_dwordx4 %0, %1, off offset:512" : "=v"(BK_[10]) : "v"(_b2));    \
    asm volatile("global_load_dwordx4 %0, %1, off offset:768" : "=v"(BK_[11]) : "v"(_b2));    \
    asm volatile("global_load_dwordx4 %0, %1, off"            : "=v"(BK_[12]) : "v"(_b3));    \
    asm volatile("global_load_dwordx4 %0, %1, off offset:256" : "=v"(BK_[13]) : "v"(_b3));    \
    asm volatile("global_load_dwordx4 %0, %1, off offset:512" : "=v"(BK_[14]) : "v"(_b3));    \
    asm volatile("global_load_dwordx4 %0, %1, off offset:768" : "=v"(BK_[15]) : "v"(_b3));    \
  }

// compute one 128-k half (4 k-steps x 4 n-frags) from LDS A + register B bank
#define CHALF(Ap_, H_, BK_)                                                                   \
  { _Pragma("unroll")                                                                         \
    for (int _sl = 0; _sl < 4; ++_sl) {                                                       \
      const int _c0 = ((H_) * 4 + _sl) * 8 + kgrp * 2;                                        \
      const f32x4 _lo = *(const f32x4*)((Ap_) + arow + (((_c0    ) ^ aswz) * 16));            \
      const f32x4 _hi = *(const f32x4*)((Ap_) + arow + (((_c0 + 1) ^ aswz) * 16));            \
      bf16x8 _av;                                                                             \
      _Pragma("unroll")                                                                       \
      for (int _j = 0; _j < 4; ++_j) { _av[_j] = (__bf16)_lo[_j]; _av[_j+4] = (__bf16)_hi[_j]; } \
      const short8 _a8 = __builtin_bit_cast(short8, _av);                                     \
      acc[0] = __builtin_amdgcn_mfma_f32_16x16x32_bf16(_a8, BK_[_sl*4+0], acc[0], 0, 0, 0);   \
      acc[1] = __builtin_amdgcn_mfma_f32_16x16x32_bf16(_a8, BK_[_sl*4+1], acc[1], 0, 0, 0);   \
      acc[2] = __builtin_amdgcn_mfma_f32_16x16x32_bf16(_a8, BK_[_sl*4+2], acc[2], 0, 0, 0);   \
      acc[3] = __builtin_amdgcn_mfma_f32_16x16x32_bf16(_a8, BK_[_sl*4+3], acc[3], 0, 0, 0);   \
    } }

#define VMCNT(n) do { asm volatile("s_waitcnt vmcnt(" #n ")" ::: "memory");                   \
                      __builtin_amdgcn_sched_barrier(0); } while (0)
#define BAR()    do { __builtin_amdgcn_s_barrier();                                           \
                      __builtin_amdgcn_sched_barrier(0); } while (0)

__global__ __launch_bounds__(512, 1)
void gcn_main(const float* __restrict__ adj, const unsigned short* __restrict__ Yt,
              const float* __restrict__ Z, float* __restrict__ out)
{
  __shared__ __align__(16) unsigned char abuf[2][65536];   // A fp32, 64 rows x 1KB, dbuf

  const int tid  = threadIdx.x;
  const int lane = tid & 63;
  const int wv   = tid >> 6;     // 0..7
  const int rg   = wv >> 1;      // 16-row strip (0..3)
  const int nh   = wv & 1;       // 64-col half
  const int m0   = blockIdx.x * 64;
  const int rlo  = lane & 15;
  const int kgrp = lane >> 4;    // 0..3

  const int arow = (rg * 16 + rlo) * 1024;            // this lane's A row byte base
  const int aswz = rlo & 7;
  const int boff = kgrp * 2048 + (nh * 64 + rlo) * 16; // per-lane B byte offset

  f32x4 acc[4];
#pragma unroll
  for (int f = 0; f < 4; ++f) acc[f] = (f32x4){0.f, 0.f, 0.f, 0.f};

  short8 bk0[16], bk1[16];

  auto stageA = [&](int buf, int kt2) {
#pragma unroll
    for (int i = 0; i < 8; ++i) {
      const int r = wv * 8 + i;                       // wave-uniform row
      const int j = lane ^ (r & 7);                   // inverse swizzle on source
      const float* as = adj + (size_t)(m0 + r) * NROWS + (size_t)kt2 * 256 + (size_t)j * 4;
      __builtin_amdgcn_global_load_lds(
          (const __attribute__((address_space(1))) void*)as,
          (__attribute__((address_space(3))) void*)(&abuf[buf][r * 1024]),
          16, 0, 2 /* NT: one-shot stream, keep Yt in L2 */);
    }
  };

  // ---- prologue: A(0),A(1) staged; B(0,0) in flight ----
  stageA(0, 0);
  stageA(1, 1);
  BLOAD(bk0, 0);

  // ---- kt = 0 (peeled: first waits differ) ----
  {
    const unsigned char* Ap = abuf[0];
    BLOAD(bk1, 1);
    VMCNT(16);                  // forces A(0), A(1), B(0,0)
    BAR();                      // A(0) visible to all waves
    CHALF(Ap, 0, bk0);
    BLOAD(bk0, 2);              // B(1,0)
    VMCNT(16);                  // forces B(0,1)
    CHALF(Ap, 1, bk1);
    BAR();
    stageA(0, 2);
  }

  // ---- steady: kt = 1 .. 62 ----
  for (int kt = 1; kt <= NTI - 2; ++kt) {
    const unsigned char* Ap = abuf[kt & 1];
    BLOAD(bk1, 2 * kt + 1);
    VMCNT(24);                  // forces B(kt,0); leaves A(kt+1)+B(kt,1)
    CHALF(Ap, 0, bk0);
    BLOAD(bk0, 2 * kt + 2);     // B(kt+1,0)
    VMCNT(16);                  // forces B(kt,1) and A(kt+1); leaves B(kt+1,0)
    CHALF(Ap, 1, bk1);
    BAR();                      // all waves done with abuf[kt&1]; A(kt+1) visible
    if (kt < NTI - 2) stageA(kt & 1, kt + 2);
  }

  // ---- kt = 63 (peeled: drain) ----
  {
    const unsigned char* Ap = abuf[1];
    BLOAD(bk1, 127);
    VMCNT(16);                  // forces B(63,0)   (A(64) was never staged)
    CHALF(Ap, 0, bk0);
    VMCNT(0);                   // forces B(63,1)
    CHALF(Ap, 1, bk1);
  }

  // epilogue: out = acc + Z.  C/D: row=(lane>>4)*4+reg, col=lane&15
  const int rowb = m0 + rg * 16 + (lane >> 4) * 4;
#pragma unroll
  for (int f = 0; f < 4; ++f) {
    const int col = nh * 64 + f * 16 + rlo;
#pragma unroll
    for (int r = 0; r < 4; ++r) {
      const size_t idx = (size_t)(rowb + r) * FDIM + col;
      out[idx] = acc[f][r] + Z[idx];
    }
  }
}

extern "C" void kernel_launch(void* const* d_in, const int* in_sizes, int n_in,
                              void* d_out, int out_size, void* d_ws, size_t ws_size,
                              hipStream_t stream) {
  const float* input  = (const float*)d_in[0];
  const float* adj    = (const float*)d_in[1];
  const float* weight = (const float*)d_in[2];
  float* out = (float*)d_out;

  unsigned short* Yt = (unsigned short*)d_ws;                           // 4MB bf16
  float* Z = (float*)((char*)d_ws + (size_t)NROWS * FDIM * 2);          // 8MB fp32

  gcn_prep<<<512, 256, 0, stream>>>(input, weight, Yt, Z);
  gcn_main<<<256, 512, 0, stream>>>(adj, Yt, Z, out);
}

// Round 5
// 198.129 us; speedup vs baseline: 1.4717x; 1.4717x over previous
//
#include <hip/hip_runtime.h>

// GraphConvolution: out = input @ W_self + (adj @ input) @ W_agg
//                       = adj @ (input @ W_agg) + input @ W_self   [associativity]
// Heavy op: adj(16384x16384 fp32, 1.07GB) @ Y(16384x128 bf16) -> memory-bound,
// floor ~168us @6.4TB/s.
//
// main (r3, unchanged): BM=64 BK=128, 512thr (8 waves: 4M x 2N), grid 256 (1 blk/CU).
//  depth-2 LDS pipeline, counted vmcnt(8), NT on adj stream, rule-21 XOR-swizzled A.
// prep (r5, new): MFMA-based. input+W staged to LDS as bf16 (XOR swizzle),
//  one 64x256x128 GEMM/block -> Z fp32 + Y bf16 written directly in tiled layout.
//
// ws: [0,4MB) Yt bf16 pre-tiled in 128-row tiles: elem = H*16384 + (ch*128+n)*8 + kin,
//     H=m>>7, ch=(m>>3)&15, kin=m&7.   [4MB,12MB) Z fp32 row-major.

#define NROWS 16384
#define FDIM  128
#define NT2   128          // K tiles of 128 in main

typedef __attribute__((ext_vector_type(4))) float f32x4;
typedef __attribute__((ext_vector_type(8))) short short8;
typedef __attribute__((ext_vector_type(8))) __bf16 bf16x8;
typedef __attribute__((ext_vector_type(4))) unsigned short ushort4v;

static __device__ __forceinline__ unsigned short f2bf(float f) {
  union { __bf16 b; unsigned short u; } cvt;
  cvt.b = (__bf16)f;   // RNE fptrunc
  return cvt.u;
}

// ---------------------------------------------------------------------------
// Kernel 1 (MFMA): Z = input @ W_self (fp32), Y = input @ W_agg (bf16, tiled).
// 256 blocks x 256 thr (4 waves), 64 rows/block. Virtual N=256: n<128 -> Z, n>=128 -> Y.
// LDS: inA [64][128] bf16, Wt [256][128] bf16 (n-major), both byte^((row|n &7)<<4).
// ---------------------------------------------------------------------------
__global__ __launch_bounds__(256, 2)
void gcn_prep(const float* __restrict__ input, const float* __restrict__ weight,
              unsigned short* __restrict__ Yt, float* __restrict__ Z)
{
  __shared__ __align__(16) unsigned short inA[8192];    // 16KB
  __shared__ __align__(16) unsigned short Wt[32768];    // 64KB
  char* inA_c = (char*)inA;
  char* Wt_c  = (char*)Wt;

  const int tid  = threadIdx.x;
  const int lane = tid & 63;
  const int wv   = tid >> 6;     // 0..3
  const int m0g  = blockIdx.x * 64;

  // stage input rows [m0g, m0g+64) as bf16, swizzled
#pragma unroll
  for (int p = 0; p < 8; ++p) {
    const int idx4 = tid + p * 256;          // [0,2048)
    const int row  = idx4 >> 5;              // 0..63
    const int k0   = (idx4 & 31) * 4;
    const f32x4 v  = *(const f32x4*)(input + (size_t)(m0g + row) * FDIM + k0);
    ushort4v u;
#pragma unroll
    for (int i = 0; i < 4; ++i) u[i] = f2bf(v[i]);
    *(ushort4v*)(inA_c + row * 256 + ((k0 * 2) ^ ((row & 7) << 4))) = u;
  }
  // stage W transposed: Wt[n][k]; n<128 = W_self col n, n>=128 = W_agg col n-128
#pragma unroll
  for (int p = 0; p < 32; ++p) {
    const int e4   = tid + p * 256;          // [0,8192)
    const int krow = e4 >> 5;                // 0..255
    const int n0   = (e4 & 31) * 4;
    const f32x4 v  = *(const f32x4*)(weight + (size_t)krow * FDIM + n0);
    const int k  = krow & 127;
    const int nb = (krow >> 7) * 128;
#pragma unroll
    for (int i = 0; i < 4; ++i) {
      const int n = nb + n0 + i;
      *(unsigned short*)(Wt_c + n * 256 + ((k * 2) ^ ((n & 7) << 4))) = f2bf(v[i]);
    }
  }
  __syncthreads();

  const int rlo  = lane & 15;
  const int kgrp = lane >> 4;
  const int arow = wv * 16 + rlo;

  f32x4 acc[16];
#pragma unroll
  for (int f = 0; f < 16; ++f) acc[f] = (f32x4){0.f, 0.f, 0.f, 0.f};

#pragma unroll
  for (int s = 0; s < 4; ++s) {
    const int kb = s * 64 + kgrp * 16;
    const short8 a8 = *(const short8*)(inA_c + arow * 256 + (kb ^ ((arow & 7) << 4)));
#pragma unroll
    for (int f = 0; f < 16; ++f) {
      const int n = f * 16 + rlo;
      const short8 b8 = *(const short8*)(Wt_c + n * 256 + (kb ^ ((n & 7) << 4)));
      acc[f] = __builtin_amdgcn_mfma_f32_16x16x32_bf16(a8, b8, acc[f], 0, 0, 0);
    }
  }

  // epilogue. C/D: row = kgrp*4 + r, col = rlo (within 16x16 frag)
  const int mg = m0g + wv * 16 + kgrp * 4;   // 4-aligned global row
  // Z (n-frags 0..7): fp32 row-major
#pragma unroll
  for (int f = 0; f < 8; ++f) {
    const int col = f * 16 + rlo;
#pragma unroll
    for (int r = 0; r < 4; ++r)
      Z[(size_t)(mg + r) * FDIM + col] = acc[f][r];
  }
  // Y (n-frags 8..15): bf16 in tiled layout; kin innermost -> 4 rows pack into 8B
  const int H = mg >> 7, ch = (mg >> 3) & 15, kin0 = mg & 7;   // kin0 in {0,4}
#pragma unroll
  for (int f = 8; f < 16; ++f) {
    const int c = f * 16 + rlo - 128;
    ushort4v u;
#pragma unroll
    for (int r = 0; r < 4; ++r) u[r] = f2bf(acc[f][r]);
    *(ushort4v*)(Yt + (size_t)H * 16384 + (size_t)(ch * 128 + c) * 8 + kin0) = u;
  }
}

// ---------------------------------------------------------------------------
// Kernel 2 (unchanged r3): out = adj @ Y + Z.  BM=64 BN=128 BK=128.
// 256 blocks x 512 thr.
// ---------------------------------------------------------------------------
__global__ __launch_bounds__(512, 1)
void gcn_main(const float* __restrict__ adj, const unsigned short* __restrict__ Yt,
              const float* __restrict__ Z, float* __restrict__ out)
{
  // per buffer: [0,32768) B bf16 tiled, [32768,65536) A fp32 swizzled (64 rows x 512B)
  __shared__ __align__(16) unsigned char lds[2][65536];

  const int tid  = threadIdx.x;
  const int lane = tid & 63;
  const int wv   = tid >> 6;     // 0..7
  const int rg   = wv >> 1;      // 16-row strip (0..3)
  const int nh   = wv & 1;       // 64-col half
  const int m0   = blockIdx.x * 64;
  const int rlo  = lane & 15;
  const int kgrp = lane >> 4;    // 0..3

  f32x4 acc[4];
#pragma unroll
  for (int f = 0; f < 4; ++f) acc[f] = (f32x4){0.f, 0.f, 0.f, 0.f};

  auto stage = [&](int buf, int kt) {
    // B tile: 32KB, 4 issues/wave, linear (pre-tiled in Yt), cached (L2-resident)
    const unsigned short* bs = Yt + (size_t)kt * 16384;
#pragma unroll
    for (int i = 0; i < 4; ++i) {
      const int q = wv * 4 + i;                     // 32 chunks of 1KB
      __builtin_amdgcn_global_load_lds(
          (const __attribute__((address_space(1))) void*)(bs + q * 512 + lane * 8),
          (__attribute__((address_space(3))) void*)(&lds[buf][q * 1024]),
          16, 0, 0);
    }
    // A tile: 64 rows x 512B = 32KB, 4 issues/wave (1KB = 2 rows each).
    // LDS dest linear; global source chunk = t ^ (row&7)  [inverse swizzle], NT policy.
#pragma unroll
    for (int i = 0; i < 4; ++i) {
      const int p     = wv * 4 + i;                 // row pair
      const int row_g = 2 * p + (lane >> 5);
      const int j     = (lane & 31) ^ (row_g & 7);
      const float* as = adj + (size_t)(m0 + row_g) * NROWS + (size_t)kt * 128 + j * 4;
      __builtin_amdgcn_global_load_lds(
          (const __attribute__((address_space(1))) void*)as,
          (__attribute__((address_space(3))) void*)(&lds[buf][32768 + p * 1024]),
          16, 0, 2 /* NT: non-temporal, don't evict Yt from L2 */);
    }
  };

  // prologue: tiles 0,1 in flight (16 ops/wave)
  stage(0, 0);
  stage(1, 1);

  const int arow = (rg * 16 + rlo) * 512;   // byte offset of this lane's A row
  const int aswz = rlo & 7;

  for (int kt = 0; kt < NT2; ++kt) {
    if (kt < NT2 - 1) {
      asm volatile("s_waitcnt vmcnt(8)" ::: "memory");   // stage(kt) landed; kt+1 in flight
    } else {
      asm volatile("s_waitcnt vmcnt(0)" ::: "memory");
    }
    __builtin_amdgcn_sched_barrier(0);
    __builtin_amdgcn_s_barrier();                       // buf[kt&1] fully staged, all waves
    __builtin_amdgcn_sched_barrier(0);

    const int buf = kt & 1;
    const unsigned char* Bp = lds[buf];
    const unsigned char* Ap = Bp + 32768;

    // A frags: k-step s (K=32): k = s*32 + kgrp*8 + {0..7} -> chunks s*8+kgrp*2, +1
    short8 a8[4];
#pragma unroll
    for (int s = 0; s < 4; ++s) {
      const int c0 = s * 8 + kgrp * 2;
      const f32x4 lo = *(const f32x4*)(Ap + arow + ((c0    ) ^ aswz) * 16);
      const f32x4 hi = *(const f32x4*)(Ap + arow + ((c0 + 1) ^ aswz) * 16);
      bf16x8 av;
#pragma unroll
      for (int j = 0; j < 4; ++j) {
        av[j]     = (__bf16)lo[j];
        av[j + 4] = (__bf16)hi[j];
      }
      a8[s] = __builtin_bit_cast(short8, av);
    }

#pragma unroll
    for (int s = 0; s < 4; ++s) {
      const int ch = s * 4 + kgrp;
#pragma unroll
      for (int f = 0; f < 4; ++f) {
        const int n = nh * 64 + f * 16 + rlo;
        const short8 b8 = *(const short8*)(Bp + (size_t)(ch * 128 + n) * 16);
        acc[f] = __builtin_amdgcn_mfma_f32_16x16x32_bf16(a8[s], b8, acc[f], 0, 0, 0);
      }
    }

    __builtin_amdgcn_s_barrier();                       // all waves done reading buf
    __builtin_amdgcn_sched_barrier(0);
    if (kt + 2 < NT2) stage(buf, kt + 2);               // overwrite freed buf
  }

  // epilogue: out = acc + Z.  C/D: row=(lane>>4)*4+reg, col=lane&15
  const int rowb = m0 + rg * 16 + (lane >> 4) * 4;
#pragma unroll
  for (int f = 0; f < 4; ++f) {
    const int col = nh * 64 + f * 16 + rlo;
#pragma unroll
    for (int r = 0; r < 4; ++r) {
      const size_t idx = (size_t)(rowb + r) * FDIM + col;
      out[idx] = acc[f][r] + Z[idx];
    }
  }
}

extern "C" void kernel_launch(void* const* d_in, const int* in_sizes, int n_in,
                              void* d_out, int out_size, void* d_ws, size_t ws_size,
                              hipStream_t stream) {
  const float* input  = (const float*)d_in[0];
  const float* adj    = (const float*)d_in[1];
  const float* weight = (const float*)d_in[2];
  float* out = (float*)d_out;

  unsigned short* Yt = (unsigned short*)d_ws;                           // 4MB bf16
  float* Z = (float*)((char*)d_ws + (size_t)NROWS * FDIM * 2);          // 8MB fp32

  gcn_prep<<<256, 256, 0, stream>>>(input, weight, Yt, Z);
  gcn_main<<<256, 512, 0, stream>>>(adj, Yt, Z, out);
}